// Round 13
// baseline (432.273 us; speedup 1.0000x reference)
//
#include <hip/hip_runtime.h>
#include <hip/hip_bf16.h>

typedef unsigned short u16;
typedef unsigned char u8;
typedef unsigned int u32;
typedef long long i64;
typedef __attribute__((ext_vector_type(4))) float f32x4;
typedef __attribute__((ext_vector_type(8))) __bf16 bf16x8;

#define DEV __device__ __forceinline__

DEV u16 f2bf(float f) {
  union { float f; unsigned u; } c; c.f = f;
  unsigned r = (c.u + 0x7fffu + ((c.u >> 16) & 1u)) >> 16;
  return (u16)r;
}

DEV float bf2f(u16 u) {
  union { u32 u; float f; } c; c.u = (u32)u << 16;
  return c.f;
}

DEV void gld_lds16(const void* g, void* l) {
  __builtin_amdgcn_global_load_lds(
      (__attribute__((address_space(1))) void*)g,
      (__attribute__((address_space(3))) void*)l, 16, 0, 0);
}

DEV f32x4 mfma_bf16(bf16x8 a, bf16x8 b, f32x4 c) {
  return __builtin_amdgcn_mfma_f32_16x16x32_bf16(a, b, c, 0, 0, 0);
}

// raw barrier that does NOT drain prefetch unless asked
DEV void bar_vm0() { asm volatile("s_waitcnt vmcnt(0) lgkmcnt(0)\n\ts_barrier" ::: "memory"); }
DEV void wait_lg0() { asm volatile("s_waitcnt lgkmcnt(0)" ::: "memory"); }

DEV u32 pack_fp8x4(float a, float b, float c, float d) {
  u32 t = __builtin_amdgcn_cvt_pk_fp8_f32(a, b, 0, false);
  t = __builtin_amdgcn_cvt_pk_fp8_f32(c, d, t, true);
  return t;
}

DEV u8 f2fp8(float v) {
  u32 t = __builtin_amdgcn_cvt_pk_fp8_f32(v, v, 0, false);
  return (u8)(t & 0xff);
}

// ---------------- fused prep ----------------
__global__ __launch_bounds__(256) void prep_kernel(const float* __restrict__ x,
                                                   const float* __restrict__ Wq,
                                                   const float* __restrict__ Wk,
                                                   const float* __restrict__ Wv,
                                                   const float* __restrict__ Wo,
                                                   const float* __restrict__ W1,
                                                   const float* __restrict__ W2,
                                                   u16* __restrict__ xb, u16* __restrict__ wqC,
                                                   u16* __restrict__ wkC, u16* __restrict__ wvC,
                                                   u16* __restrict__ woT, u16* __restrict__ w1T,
                                                   u16* __restrict__ w2T) {
  int b = blockIdx.x;
  int tid = threadIdx.x;
  if (b < 8192) {  // plain cvt jobs
    const float* in;
    u16* out;
    int i;
    if (b < 2048) { in = x; out = xb; i = b * 256 + tid; }
    else {
      int idx = b - 2048;
      int job = idx >> 11;
      in = job == 0 ? Wq : (job == 1 ? Wk : Wv);
      out = job == 0 ? wqC : (job == 1 ? wkC : wvC);
      i = (idx & 2047) * 256 + tid;
    }
    float4 v = ((const float4*)in)[i];
    ushort4 o;
    o.x = f2bf(v.x); o.y = f2bf(v.y); o.z = f2bf(v.z); o.w = f2bf(v.w);
    ((ushort4*)out)[i] = o;
    return;
  }
  int idx = b - 8192;
  const float* in;
  u16* out;
  int R, C, bx, by;
  if (idx < 2048) { in = Wo; out = woT; R = 4096; C = 512; by = idx >> 4; bx = idx & 15; }
  else if (idx < 3072) { int rr = idx - 2048; in = W1; out = w1T; R = 512; C = 2048; by = rr >> 6; bx = rr & 63; }
  else { int rr = idx - 3072; in = W2; out = w2T; R = 2048; C = 512; by = rr >> 4; bx = rr & 15; }
  __shared__ float t[32][33];
  int c0 = bx * 32, r0 = by * 32;
  int tx = tid & 31, ty = tid >> 5;
#pragma unroll
  for (int i = 0; i < 4; ++i) {
    int rr2 = ty + i * 8;
    t[rr2][tx] = in[(size_t)(r0 + rr2) * C + c0 + tx];
  }
  __syncthreads();
#pragma unroll
  for (int i = 0; i < 4; ++i) {
    int cc = ty + i * 8;
    out[(size_t)(c0 + cc) * R + r0 + tx] = f2bf(t[tx][cc]);
  }
}

// ---------------- biasP: biasP[(h,e)] = sum_e2 Wo[(h,e2),e] * bv[(h,e2)] ----------------
__global__ __launch_bounds__(256) void biasp_kernel(const float* __restrict__ Wo,
                                                    const float* __restrict__ bv,
                                                    float* __restrict__ biasP) {
  int b = blockIdx.x;  // 32 = h(8) x ec(4)
  int h = b >> 2, ec = b & 3;
  int t = threadIdx.x;
  int tl = t & 127, half = t >> 7;
  int e = ec * 128 + tl;
  float acc = 0.f;
  for (int i = 0; i < 256; ++i) {
    int e2 = half * 256 + i;
    acc += Wo[(size_t)(h * 512 + e2) * 512 + e] * bv[h * 512 + e2];
  }
  __shared__ float sh[2][128];
  sh[half][tl] = acc;
  __syncthreads();
  if (half == 0) biasP[h * 512 + e] = sh[0][tl] + sh[1][tl];
}

// ---------------- batched per-head 512x512x512 TN GEMM (8 heads along grid rows) ----------
template <int AMODE>
__global__ __launch_bounds__(256) void gemm_bat(const u16* __restrict__ A,
                                                const u16* __restrict__ B,
                                                u16* __restrict__ out) {
  constexpr int BK = 64, BM = 128, BN = 128;
  __shared__ u16 As[2][BM * BK];
  __shared__ u16 Bs[2][BN * BK];
  const int tid = threadIdx.x;
  const int wave = tid >> 6, lane = tid & 63;
  const int r = lane & 15, g = lane >> 4;
  const int row0 = blockIdx.y * BM, col0 = blockIdx.x * BN;
  const int head = row0 >> 9;
  const int wr = (wave >> 1) * 64, wc = (wave & 1) * 64;

  auto stage = [&](int kt, int p) {
#pragma unroll
    for (int i = 0; i < 4; ++i) {
      int bi = i * 256 + wave * 64;
      int c = bi + lane;
      int row = c >> 3, ch = (c & 7) ^ (row & 7);
      size_t aoff;
      if constexpr (AMODE == 0)
        aoff = (size_t)(row0 + row) * 512 + kt + ch * 8;
      else
        aoff = (size_t)((row0 + row) & 511) * 4096 + head * 512 + kt + ch * 8;
      gld_lds16(A + aoff, &As[p][(size_t)bi * 8]);
    }
#pragma unroll
    for (int i = 0; i < 4; ++i) {
      int bi = i * 256 + wave * 64;
      int c = bi + lane;
      int row = c >> 3, ch = (c & 7) ^ (row & 7);
      gld_lds16(B + (size_t)(head * 512 + col0 + row) * 512 + kt + ch * 8,
                &Bs[p][(size_t)bi * 8]);
    }
  };

  f32x4 acc[4][4] = {};
  stage(0, 0);
  for (int t = 0; t < 8; ++t) {
    const int p = t & 1;
    bar_vm0();
    if (t < 7) stage((t + 1) * BK, p ^ 1);
    __builtin_amdgcn_s_setprio(1);
#pragma unroll
    for (int kk = 0; kk < 2; ++kk) {
      bf16x8 af[4], bfv[4];
#pragma unroll
      for (int m = 0; m < 4; ++m)
        af[m] = *(const bf16x8*)(&As[p][(wr + m * 16 + r) * BK + (((kk * 4 + g) ^ (r & 7))) * 8]);
#pragma unroll
      for (int n = 0; n < 4; ++n)
        bfv[n] = *(const bf16x8*)(&Bs[p][(wc + n * 16 + r) * BK + (((kk * 4 + g) ^ (r & 7))) * 8]);
#pragma unroll
      for (int m = 0; m < 4; ++m)
#pragma unroll
        for (int n = 0; n < 4; ++n)
          acc[m][n] = mfma_bf16(af[m], bfv[n], acc[m][n]);
    }
    __builtin_amdgcn_s_setprio(0);
  }
#pragma unroll
  for (int m = 0; m < 4; ++m)
#pragma unroll
    for (int n = 0; n < 4; ++n)
#pragma unroll
      for (int j = 0; j < 4; ++j)
        out[(size_t)(row0 + wr + m * 16 + g * 4 + j) * 512 + col0 + wc + n * 16 + r] =
            f2bf(acc[m][n][j]);
}

// ---------------- generic TN bf16 GEMM: C = A[M,K] * B[N,K]^T ----------------
// MODE 0: q2 epilogue -> [B,H,S,512] bf16 (+bias per (h,e)).
// MODE 1: v'T epilogue -> FP8 e4m3, kv-tiled [B,H][t=S/32][e=512][32] (+bias per row).
// MODE 2: f32 out (+bias on z==0), split-K planes.  MODE 3: bf16 out + bias + relu.
template <int NT, int BM, int BN, int WM, int WN, int MODE, int SPLITK>
__global__ __launch_bounds__(NT) void gemm_tn(const u16* __restrict__ A,
                                              const u16* __restrict__ B, int N, int K,
                                              void* __restrict__ out0,
                                              const float* __restrict__ bias0) {
  constexpr int BK = 64;
  constexpr int MF = WM / 16, NF = WN / 16;
  constexpr int WC = BN / WN;
  constexpr int AI = (BM * BK / 8) / NT;
  constexpr int BI = (BN * BK / 8) / NT;
  __shared__ u16 As[2][BM * BK];
  __shared__ u16 Bs[2][BN * BK];
  const int tid = threadIdx.x;
  const int wave = tid >> 6, lane = tid & 63;
  const int r = lane & 15, g = lane >> 4;
  const int row0 = blockIdx.y * BM, col0 = blockIdx.x * BN;
  const int wr = (wave / WC) * WM, wc = (wave % WC) * WN;
  const int KS = K * SPLITK;
  const int kb0 = blockIdx.z * K;

  auto stage = [&](int kt, int p) {
#pragma unroll
    for (int i = 0; i < AI; ++i) {
      int bi = i * NT + wave * 64;
      int c = bi + lane;
      int row = c >> 3, ch = (c & 7) ^ (row & 7);
      gld_lds16(A + (size_t)(row0 + row) * KS + kb0 + kt + ch * 8, &As[p][(size_t)bi * 8]);
    }
#pragma unroll
    for (int i = 0; i < BI; ++i) {
      int bi = i * NT + wave * 64;
      int c = bi + lane;
      int row = c >> 3, ch = (c & 7) ^ (row & 7);
      gld_lds16(B + (size_t)(col0 + row) * KS + kb0 + kt + ch * 8, &Bs[p][(size_t)bi * 8]);
    }
  };

  f32x4 acc[MF][NF] = {};
  const int nt = K / BK;

  stage(0, 0);
  for (int t = 0; t < nt; ++t) {
    const int p = t & 1;
    bar_vm0();
    if (t + 1 < nt) stage((t + 1) * BK, p ^ 1);
    __builtin_amdgcn_s_setprio(1);
#pragma unroll
    for (int kk = 0; kk < 2; ++kk) {
      bf16x8 af[MF], bfv[NF];
#pragma unroll
      for (int m = 0; m < MF; ++m)
        af[m] = *(const bf16x8*)(&As[p][(wr + m * 16 + r) * BK + (((kk * 4 + g) ^ (r & 7))) * 8]);
#pragma unroll
      for (int n = 0; n < NF; ++n)
        bfv[n] = *(const bf16x8*)(&Bs[p][(wc + n * 16 + r) * BK + (((kk * 4 + g) ^ (r & 7))) * 8]);
#pragma unroll
      for (int m = 0; m < MF; ++m)
#pragma unroll
        for (int n = 0; n < NF; ++n)
          acc[m][n] = mfma_bf16(af[m], bfv[n], acc[m][n]);
    }
    __builtin_amdgcn_s_setprio(0);
  }

  const size_t moff = (size_t)blockIdx.z * gridDim.y * BM * N;
#pragma unroll
  for (int m = 0; m < MF; ++m) {
#pragma unroll
    for (int n = 0; n < NF; ++n) {
      int gcol = col0 + wc + n * 16 + r;
#pragma unroll
      for (int j = 0; j < 4; ++j) {
        int grow = row0 + wr + m * 16 + g * 4 + j;
        float val = acc[m][n][j];
        if constexpr (MODE == 0) {
          int he = gcol;
          val += bias0[he];
          int bb = grow >> 10, s = grow & 1023;
          size_t off = (((size_t)(bb * 8 + (he >> 9)) * 1024 + s) * 512) + (he & 511);
          ((u16*)out0)[off] = f2bf(val);
        } else if constexpr (MODE == 1) {
          val += bias0[grow];
          int h = grow >> 9, e_ = grow & 511;
          int bbb = gcol >> 10, s = gcol & 1023;
          size_t off = ((size_t)(bbb * 8 + h)) * 524288 + (size_t)(s >> 5) * 16384 +
                       (size_t)e_ * 32 + (s & 31);
          ((u8*)out0)[off] = f2fp8(val);
        } else if constexpr (MODE == 2) {
          if (SPLITK == 1 || blockIdx.z == 0) val += bias0[gcol];
          ((float*)out0)[moff + (size_t)grow * N + gcol] = val;
        } else {
          float v2 = fmaxf(val + bias0[gcol], 0.0f);
          ((u16*)out0)[(size_t)grow * N + gcol] = f2bf(v2);
        }
      }
    }
  }
}

// ---------------- flash attention (v11: bf16 QK from LDS, FP8 V direct from L2) ----------
// 256 blocks (1/CU), XCD-swizzled. 8 waves x 16 q-rows x full 512 e.
// K bf16 double-buffered LDS (32KB/tile); V fp8 kv-tiled in global, read coalesced
// (512B/wave burst) straight into registers during PV -- no V LDS at all.
__global__ __launch_bounds__(512, 2) void flash_kernel(const u16* __restrict__ qg,
                                                       const u16* __restrict__ kg,
                                                       const u8* __restrict__ vtg,
                                                       u16* __restrict__ concat) {
  constexpr float SCALE = 0.04419417382415922f;  // 1/sqrt(512)
  __shared__ u16 Ks[2][32 * 512];            // 64KB
  __shared__ __align__(16) u32 PsP[8][128];  // 4KB

  const int tid = threadIdx.x;
  const int wave = tid >> 6, lane = tid & 63;
  const int r = lane & 15, g = lane >> 4;
  const int bx = blockIdx.x;
  const int xcd = bx & 7, slot = bx >> 3;
  const int bh = xcd * 4 + (slot >> 3);
  const int qt = slot & 7;
  const int bb = bh >> 3, hh = bh & 7;
  const size_t hbase = (size_t)bh * 1024 * 512;
  const u16* qp = qg + hbase;
  const u16* kp = kg + (size_t)bb * 1024 * 512;  // K = xb[b] (head-independent)
  const u8* vp = vtg + (size_t)bh * 524288;      // v' fp8 tiled [32t][512e][32kv]
  const int q0 = qt * 128;

  bf16x8 q[16];
#pragma unroll
  for (int kk = 0; kk < 16; ++kk)
    q[kk] = *(const bf16x8*)(qp + (size_t)(q0 + wave * 16 + r) * 512 + kk * 32 + g * 8);

  const int krow8 = lane >> 3, kch = (lane & 7) ^ (lane >> 3);
  auto stageK = [&](int t, int p) {
    int kv = t * 32;
#pragma unroll
    for (int j = 0; j < 4; ++j) {
      int id = wave * 4 + j;
      gld_lds16(kp + (size_t)(kv + j * 8 + krow8) * 512 + wave * 64 + kch * 8,
                &Ks[p][id * 512]);
    }
  };

  f32x4 o[32] = {};
  float mrun = -1e30f, lrun = 0.f;

  stageK(0, 0);

  const int krh = (r >> 3) * 512;
  const int ke0 = (r & 7) * 64 + ((g ^ (r & 7)) * 8);
  const int ke1 = (r & 7) * 64 + (((4 + g) ^ (r & 7)) * 8);
  const u8* vbl = vp + r * 32 + g * 8;  // per-lane V base within a tile
  const int psw = r & 6;

  for (int t = 0; t < 32; ++t) {
    const int p = t & 1;
    bar_vm0();
    if (t < 31) stageK(t + 1, p ^ 1);

    // S^T = K * Q (bf16): lane (r,g) gets S[q=r][kv = h*16 + g*4 + j]
    __builtin_amdgcn_s_setprio(1);
    f32x4 a0 = {}, a1 = {}, b0 = {}, b1 = {};
#pragma unroll
    for (int kc = 0; kc < 8; ++kc) {
      const u16* kb = &Ks[p][kc * 2048 + krh];
      bf16x8 kf00 = *(const bf16x8*)(kb + ke0);
      bf16x8 kf01 = *(const bf16x8*)(kb + 1024 + ke0);
      bf16x8 kf10 = *(const bf16x8*)(kb + ke1);
      bf16x8 kf11 = *(const bf16x8*)(kb + 1024 + ke1);
      a0 = mfma_bf16(kf00, q[2 * kc], a0);
      b0 = mfma_bf16(kf01, q[2 * kc], b0);
      a1 = mfma_bf16(kf10, q[2 * kc + 1], a1);
      b1 = mfma_bf16(kf11, q[2 * kc + 1], b1);
    }
    __builtin_amdgcn_s_setprio(0);
    f32x4 s0 = a0 + a1;
    f32x4 s1 = b0 + b1;

    // issue first V batch early: latency hides under softmax
    const u8* vb = vbl + (size_t)t * 16384;
    i64 vr[16];
#pragma unroll
    for (int k = 0; k < 16; ++k) vr[k] = *(const i64*)(vb + k * 512);

    float m8 = -1e30f;
#pragma unroll
    for (int j = 0; j < 4; ++j) {
      s0[j] *= SCALE;
      s1[j] *= SCALE;
      m8 = fmaxf(m8, fmaxf(s0[j], s1[j]));
    }
    m8 = fmaxf(m8, __shfl_xor(m8, 16));
    m8 = fmaxf(m8, __shfl_xor(m8, 32));
    if (__any(m8 - mrun > 6.0f)) {  // defer-max: P bounded by e^6=403 < fp8 max 448
      float mn = fmaxf(mrun, m8);
      float rs = __expf(mrun - mn);
      mrun = mn;
      lrun *= rs;
#pragma unroll
      for (int j = 0; j < 4; ++j) {
        float rsj = __shfl(rs, (lane & 48) | (g * 4 + j));
#pragma unroll
        for (int n = 0; n < 32; ++n) o[n][j] *= rsj;
      }
    }
    f32x4 p0, p1;
    float ls = 0.f;
#pragma unroll
    for (int j = 0; j < 4; ++j) {
      p0[j] = __expf(s0[j] - mrun);
      p1[j] = __expf(s1[j] - mrun);
      ls += p0[j] + p1[j];
    }
    ls += __shfl_xor(ls, 16);
    ls += __shfl_xor(ls, 32);
    lrun += ls;

    // P (fp8) into per-wave buffer: logical word w = kv>>2, physical = w ^ (r&6)
    {
      u32* pw = PsP[wave];
      u32 wA = pack_fp8x4(p0[0], p0[1], p0[2], p0[3]);
      u32 wB = pack_fp8x4(p1[0], p1[1], p1[2], p1[3]);
      pw[r * 8 + (g ^ psw)] = wA;
      pw[r * 8 + ((4 + g) ^ psw)] = wB;
    }
    wait_lg0();  // wave-private buffer: own writes visible, no barrier

    i64 pa = *(const i64*)&PsP[wave][r * 8 + ((2 * g) ^ psw)];
    __builtin_amdgcn_s_setprio(1);
#pragma unroll
    for (int n = 0; n < 16; ++n)
      o[n] = __builtin_amdgcn_mfma_f32_16x16x32_fp8_fp8(pa, vr[n], o[n], 0, 0, 0);
    __builtin_amdgcn_s_setprio(0);
#pragma unroll
    for (int k = 0; k < 16; ++k) vr[k] = *(const i64*)(vb + 8192 + k * 512);
    __builtin_amdgcn_s_setprio(1);
#pragma unroll
    for (int n = 0; n < 16; ++n)
      o[16 + n] = __builtin_amdgcn_mfma_f32_16x16x32_fp8_fp8(pa, vr[n], o[16 + n], 0, 0, 0);
    __builtin_amdgcn_s_setprio(0);
  }

  float invl = 1.0f / lrun;
#pragma unroll
  for (int j = 0; j < 4; ++j) {
    float inv = __shfl(invl, (lane & 48) | (g * 4 + j));
    int srow = q0 + wave * 16 + g * 4 + j;
    size_t rowoff = ((size_t)bb * 1024 + srow) * 4096;
#pragma unroll
    for (int n = 0; n < 32; ++n) {
      int ocol = hh * 512 + n * 16 + r;
      concat[rowoff + ocol] = f2bf(o[n][j] * inv);
    }
  }
}

// ------- residual add + layernorm; optionally sums 8 bf16 head-chunks (cc8) + bias -------
__global__ __launch_bounds__(128) void add_ln_kernel(const float* __restrict__ xin,
                                                     const u16* __restrict__ cc8,
                                                     const float* __restrict__ addin,
                                                     const float* __restrict__ addin2,
                                                     const float* __restrict__ bias,
                                                     const float* __restrict__ gamma,
                                                     const float* __restrict__ beta,
                                                     float* __restrict__ yout,
                                                     u16* __restrict__ ybout) {
  int row = blockIdx.x;
  int t = threadIdx.x;
  float4 xv = ((const float4*)(xin + (size_t)row * 512))[t];
  float v0 = xv.x, v1 = xv.y, v2 = xv.z, v3 = xv.w;
  if (cc8) {
    const u16* cr = cc8 + (size_t)row * 4096 + t * 4;
#pragma unroll
    for (int h = 0; h < 8; ++h) {
      ushort4 u = *(const ushort4*)(cr + h * 512);
      v0 += bf2f(u.x); v1 += bf2f(u.y); v2 += bf2f(u.z); v3 += bf2f(u.w);
    }
  }
  if (addin) {
    float4 av = ((const float4*)(addin + (size_t)row * 512))[t];
    v0 += av.x; v1 += av.y; v2 += av.z; v3 += av.w;
  }
  if (addin2) {
    float4 bv2 = ((const float4*)(addin2 + (size_t)row * 512))[t];
    v0 += bv2.x; v1 += bv2.y; v2 += bv2.z; v3 += bv2.w;
  }
  if (bias) {
    float4 b4 = ((const float4*)bias)[t];
    v0 += b4.x; v1 += b4.y; v2 += b4.z; v3 += b4.w;
  }
  float s1 = v0 + v1 + v2 + v3;
  float s2 = v0 * v0 + v1 * v1 + v2 * v2 + v3 * v3;
#pragma unroll
  for (int d = 1; d < 64; d <<= 1) {
    s1 += __shfl_xor(s1, d);
    s2 += __shfl_xor(s2, d);
  }
  __shared__ float sh[4];
  int wv = t >> 6;
  if ((t & 63) == 0) { sh[wv * 2] = s1; sh[wv * 2 + 1] = s2; }
  __syncthreads();
  s1 = sh[0] + sh[2];
  s2 = sh[1] + sh[3];
  float mean = s1 * (1.0f / 512.0f);
  float var = s2 * (1.0f / 512.0f) - mean * mean;
  float rstd = rsqrtf(var + 1e-6f);
  float4 gv = ((const float4*)gamma)[t];
  float4 bv = ((const float4*)beta)[t];
  float o0 = (v0 - mean) * rstd * gv.x + bv.x;
  float o1 = (v1 - mean) * rstd * gv.y + bv.y;
  float o2 = (v2 - mean) * rstd * gv.z + bv.z;
  float o3 = (v3 - mean) * rstd * gv.w + bv.w;
  float4 ov; ov.x = o0; ov.y = o1; ov.z = o2; ov.w = o3;
  ((float4*)(yout + (size_t)row * 512))[t] = ov;
  if (ybout) {
    ushort4 ub;
    ub.x = f2bf(o0); ub.y = f2bf(o1); ub.z = f2bf(o2); ub.w = f2bf(o3);
    ((ushort4*)(ybout + (size_t)row * 512))[t] = ub;
  }
}

extern "C" void kernel_launch(void* const* d_in, const int* in_sizes, int n_in, void* d_out,
                              int out_size, void* d_ws, size_t ws_size, hipStream_t stream) {
  (void)in_sizes; (void)n_in; (void)out_size; (void)ws_size;
  const float* x   = (const float*)d_in[0];
  const float* Wq  = (const float*)d_in[1];
  const float* bq  = (const float*)d_in[2];
  const float* Wk  = (const float*)d_in[3];
  const float* bk  = (const float*)d_in[4];  // drops out of softmax (row-invariant terms)
  const float* Wv  = (const float*)d_in[5];
  const float* bv  = (const float*)d_in[6];
  const float* Wo  = (const float*)d_in[7];
  const float* bo  = (const float*)d_in[8];
  const float* g1  = (const float*)d_in[9];
  const float* be1 = (const float*)d_in[10];
  const float* W1  = (const float*)d_in[11];
  const float* b1  = (const float*)d_in[12];
  const float* W2  = (const float*)d_in[13];
  const float* b2  = (const float*)d_in[14];
  const float* g2  = (const float*)d_in[15];
  const float* be2 = (const float*)d_in[16];
  (void)bk;

  char* ws = (char*)d_ws;
  const size_t MB = 1024 * 1024;
  u16*   xb    = (u16*)(ws + 0);          // 4MB
  u16*   wqC   = (u16*)(ws + 4 * MB);     // 4MB
  u16*   wkC   = (u16*)(ws + 8 * MB);     // 4MB
  u16*   wvC   = (u16*)(ws + 12 * MB);    // 4MB
  u16*   woT   = (u16*)(ws + 16 * MB);    // 4MB
  u16*   w1T   = (u16*)(ws + 20 * MB);    // 2MB
  u16*   w2T   = (u16*)(ws + 22 * MB);    // 2MB
  float* biasP = (float*)(ws + 24 * MB);  // 16KB
  u16*   mhT   = (u16*)(ws + 26 * MB);    // 4MB
  u16*   nhT   = (u16*)(ws + 30 * MB);    // 4MB
  u16*   qb    = (u16*)(ws + 34 * MB);    // 32MB
  u8*    vTb   = (u8*)(ws + 66 * MB);     // 16MB (fp8 kv-tiled)
  u16*   cc    = (u16*)(ws + 98 * MB);    // 32MB
  float* y     = (float*)(ws + 4 * MB);   // 8MB (reuse wqC/wkC after precomputes)
  u16*   yb    = (u16*)(ws + 26 * MB);    // 4MB (reuse mhT after q2)
  u16*   ff1   = (u16*)(ws + 34 * MB);    // 16MB (reuse qb after flash)
  float* ff2a  = (float*)(ws + 50 * MB);  // 8MB
  float* ff2b  = (float*)(ws + 58 * MB);  // 8MB

  prep_kernel<<<12288, 256, 0, stream>>>(x, Wq, Wk, Wv, Wo, W1, W2, xb, wqC, wkC, wvC,
                                         woT, w1T, w2T);
  biasp_kernel<<<32, 256, 0, stream>>>(Wo, bv, biasP);
  // mhT[(h,dp),d] = sum_e Wk[h,dp,e]*Wq[h,d,e]  (= (Wq Wk^T)^T per head)
  gemm_bat<0><<<dim3(4, 32), 256, 0, stream>>>(wkC, wqC, mhT);
  // nhT[(h,e),d] = sum_e2 Wo[(h,e2),e]*Wv[h,d,e2]  (= (Wv Wo_h)^T per head)
  gemm_bat<1><<<dim3(4, 32), 256, 0, stream>>>(woT, wvC, nhT);
  // q2 = x @ Mh (+bq) -> [B,H,S,512] bf16
  gemm_tn<512, 256, 256, 128, 64, 0, 1><<<dim3(16, 16), 512, 0, stream>>>(xb, mhT, 4096, 512, qb, bq);
  // v'^T = (x @ Nh + biasP) -> fp8 kv-tiled [B,H][32][512][32]
  gemm_tn<512, 256, 256, 128, 64, 1, 1><<<dim3(16, 16), 512, 0, stream>>>(nhT, xb, 4096, 512, vTb, biasP);
  // attention with K = xb (raw x, shared across heads), V fp8 from L2
  flash_kernel<<<256, 512, 0, stream>>>(qb, xb, vTb, cc);
  // LN1: x + sum_h heads'_h + bo
  add_ln_kernel<<<4096, 128, 0, stream>>>(x, cc, nullptr, nullptr, bo, g1, be1, y, yb);
  gemm_tn<256, 128, 128, 64, 64, 3, 1><<<dim3(16, 32), 256, 0, stream>>>(yb, w1T, 2048, 512, ff1, b1);
  gemm_tn<256, 64, 128, 32, 64, 2, 2><<<dim3(4, 64, 2), 256, 0, stream>>>(ff1, w2T, 512, 1024, ff2a, b2);
  add_ln_kernel<<<4096, 128, 0, stream>>>(y, nullptr, ff2a, ff2b, nullptr, g2, be2, (float*)d_out, nullptr);
}

// Round 14
// 247.103 us; speedup vs baseline: 1.7494x; 1.7494x over previous
//
#include <hip/hip_runtime.h>
#include <hip/hip_bf16.h>

typedef unsigned short u16;
typedef unsigned int u32;
typedef __attribute__((ext_vector_type(4))) float f32x4;
typedef __attribute__((ext_vector_type(8))) __bf16 bf16x8;

#define DEV __device__ __forceinline__

DEV u16 f2bf(float f) {
  union { float f; unsigned u; } c; c.f = f;
  unsigned r = (c.u + 0x7fffu + ((c.u >> 16) & 1u)) >> 16;
  return (u16)r;
}

DEV float bf2f(u16 u) {
  union { u32 u; float f; } c; c.u = (u32)u << 16;
  return c.f;
}

DEV void gld_lds16(const void* g, void* l) {
  __builtin_amdgcn_global_load_lds(
      (__attribute__((address_space(1))) void*)g,
      (__attribute__((address_space(3))) void*)l, 16, 0, 0);
}

DEV f32x4 mfma_bf16(bf16x8 a, bf16x8 b, f32x4 c) {
  return __builtin_amdgcn_mfma_f32_16x16x32_bf16(a, b, c, 0, 0, 0);
}

// raw barrier that does NOT drain prefetch unless asked
DEV void bar_vm0() { asm volatile("s_waitcnt vmcnt(0) lgkmcnt(0)\n\ts_barrier" ::: "memory"); }
DEV void wait_lg0() { asm volatile("s_waitcnt lgkmcnt(0)" ::: "memory"); }

DEV u32 cvt_pk_bf16(float lo, float hi) {
  u32 d;
  asm("v_cvt_pk_bf16_f32 %0, %1, %2" : "=v"(d) : "v"(lo), "v"(hi));
  return d;
}

// ---------------- fused prep ----------------
// [0,2048): cvt x -> xb.  [2048,8192): cvt Wq/Wk/Wv -> wqC/wkC/wvC (plain).
// [8192,10240): transpose Wo -> woT. [10240,11264): W1 -> w1T. [11264,12288): W2 -> w2T.
__global__ __launch_bounds__(256) void prep_kernel(const float* __restrict__ x,
                                                   const float* __restrict__ Wq,
                                                   const float* __restrict__ Wk,
                                                   const float* __restrict__ Wv,
                                                   const float* __restrict__ Wo,
                                                   const float* __restrict__ W1,
                                                   const float* __restrict__ W2,
                                                   u16* __restrict__ xb, u16* __restrict__ wqC,
                                                   u16* __restrict__ wkC, u16* __restrict__ wvC,
                                                   u16* __restrict__ woT, u16* __restrict__ w1T,
                                                   u16* __restrict__ w2T) {
  int b = blockIdx.x;
  int tid = threadIdx.x;
  if (b < 8192) {  // plain cvt jobs
    const float* in;
    u16* out;
    int i;
    if (b < 2048) { in = x; out = xb; i = b * 256 + tid; }
    else {
      int idx = b - 2048;
      int job = idx >> 11;
      in = job == 0 ? Wq : (job == 1 ? Wk : Wv);
      out = job == 0 ? wqC : (job == 1 ? wkC : wvC);
      i = (idx & 2047) * 256 + tid;
    }
    float4 v = ((const float4*)in)[i];
    ushort4 o;
    o.x = f2bf(v.x); o.y = f2bf(v.y); o.z = f2bf(v.z); o.w = f2bf(v.w);
    ((ushort4*)out)[i] = o;
    return;
  }
  int idx = b - 8192;
  const float* in;
  u16* out;
  int R, C, bx, by;
  if (idx < 2048) { in = Wo; out = woT; R = 4096; C = 512; by = idx >> 4; bx = idx & 15; }
  else if (idx < 3072) { int rr = idx - 2048; in = W1; out = w1T; R = 512; C = 2048; by = rr >> 6; bx = rr & 63; }
  else { int rr = idx - 3072; in = W2; out = w2T; R = 2048; C = 512; by = rr >> 4; bx = rr & 15; }
  __shared__ float t[32][33];
  int c0 = bx * 32, r0 = by * 32;
  int tx = tid & 31, ty = tid >> 5;
#pragma unroll
  for (int i = 0; i < 4; ++i) {
    int rr2 = ty + i * 8;
    t[rr2][tx] = in[(size_t)(r0 + rr2) * C + c0 + tx];
  }
  __syncthreads();
#pragma unroll
  for (int i = 0; i < 4; ++i) {
    int cc = ty + i * 8;
    out[(size_t)(c0 + cc) * R + r0 + tx] = f2bf(t[tx][cc]);
  }
}

// ---------------- biasP: biasP[(h,e)] = sum_e2 Wo[(h,e2),e] * bv[(h,e2)] ----------------
__global__ __launch_bounds__(256) void biasp_kernel(const float* __restrict__ Wo,
                                                    const float* __restrict__ bv,
                                                    float* __restrict__ biasP) {
  int b = blockIdx.x;  // 32 = h(8) x ec(4)
  int h = b >> 2, ec = b & 3;
  int t = threadIdx.x;
  int tl = t & 127, half = t >> 7;
  int e = ec * 128 + tl;
  float acc = 0.f;
  for (int i = 0; i < 256; ++i) {
    int e2 = half * 256 + i;
    acc += Wo[(size_t)(h * 512 + e2) * 512 + e] * bv[h * 512 + e2];
  }
  __shared__ float sh[2][128];
  sh[half][tl] = acc;
  __syncthreads();
  if (half == 0) biasP[h * 512 + e] = sh[0][tl] + sh[1][tl];
}

// ---------------- batched per-head 512x512x512 TN GEMM (8 heads along grid rows) ----------
// AMODE 0 (mhT): C[(h,dp),d] = sum_e A[(h,dp),e] * B[(h,d),e]   (A contig rows, stride 512)
// AMODE 1 (nhT): C[(h,e),d]  = sum_e2 A'[e, h*512+e2] * B[(h,d),e2]  (A = woT, stride 4096)
template <int AMODE>
__global__ __launch_bounds__(256) void gemm_bat(const u16* __restrict__ A,
                                                const u16* __restrict__ B,
                                                u16* __restrict__ out) {
  constexpr int BK = 64, BM = 128, BN = 128;
  __shared__ u16 As[2][BM * BK];
  __shared__ u16 Bs[2][BN * BK];
  const int tid = threadIdx.x;
  const int wave = tid >> 6, lane = tid & 63;
  const int r = lane & 15, g = lane >> 4;
  const int row0 = blockIdx.y * BM, col0 = blockIdx.x * BN;
  const int head = row0 >> 9;
  const int wr = (wave >> 1) * 64, wc = (wave & 1) * 64;

  auto stage = [&](int kt, int p) {
#pragma unroll
    for (int i = 0; i < 4; ++i) {
      int bi = i * 256 + wave * 64;
      int c = bi + lane;
      int row = c >> 3, ch = (c & 7) ^ (row & 7);
      size_t aoff;
      if constexpr (AMODE == 0)
        aoff = (size_t)(row0 + row) * 512 + kt + ch * 8;
      else
        aoff = (size_t)((row0 + row) & 511) * 4096 + head * 512 + kt + ch * 8;
      gld_lds16(A + aoff, &As[p][(size_t)bi * 8]);
    }
#pragma unroll
    for (int i = 0; i < 4; ++i) {
      int bi = i * 256 + wave * 64;
      int c = bi + lane;
      int row = c >> 3, ch = (c & 7) ^ (row & 7);
      gld_lds16(B + (size_t)(head * 512 + col0 + row) * 512 + kt + ch * 8,
                &Bs[p][(size_t)bi * 8]);
    }
  };

  f32x4 acc[4][4] = {};
  stage(0, 0);
  for (int t = 0; t < 8; ++t) {
    const int p = t & 1;
    bar_vm0();
    if (t < 7) stage((t + 1) * BK, p ^ 1);
    __builtin_amdgcn_s_setprio(1);
#pragma unroll
    for (int kk = 0; kk < 2; ++kk) {
      bf16x8 af[4], bfv[4];
#pragma unroll
      for (int m = 0; m < 4; ++m)
        af[m] = *(const bf16x8*)(&As[p][(wr + m * 16 + r) * BK + (((kk * 4 + g) ^ (r & 7))) * 8]);
#pragma unroll
      for (int n = 0; n < 4; ++n)
        bfv[n] = *(const bf16x8*)(&Bs[p][(wc + n * 16 + r) * BK + (((kk * 4 + g) ^ (r & 7))) * 8]);
#pragma unroll
      for (int m = 0; m < 4; ++m)
#pragma unroll
        for (int n = 0; n < 4; ++n)
          acc[m][n] = mfma_bf16(af[m], bfv[n], acc[m][n]);
    }
    __builtin_amdgcn_s_setprio(0);
  }
#pragma unroll
  for (int m = 0; m < 4; ++m)
#pragma unroll
    for (int n = 0; n < 4; ++n)
#pragma unroll
      for (int j = 0; j < 4; ++j)
        out[(size_t)(row0 + wr + m * 16 + g * 4 + j) * 512 + col0 + wc + n * 16 + r] =
            f2bf(acc[m][n][j]);
}

// ---------------- generic TN bf16 GEMM: C = A[M,K] * B[N,K]^T ----------------
// MODE 0: q2 epilogue -> [B,H,S,512] bf16 (+bias per (h,e)).  MODE 1: v'T epilogue.
// MODE 2: f32 out (+bias on z==0), split-K planes.  MODE 3: bf16 out + bias + relu.
template <int NT, int BM, int BN, int WM, int WN, int MODE, int SPLITK>
__global__ __launch_bounds__(NT) void gemm_tn(const u16* __restrict__ A,
                                              const u16* __restrict__ B, int N, int K,
                                              void* __restrict__ out0,
                                              const float* __restrict__ bias0) {
  constexpr int BK = 64;
  constexpr int MF = WM / 16, NF = WN / 16;
  constexpr int WC = BN / WN;
  constexpr int AI = (BM * BK / 8) / NT;
  constexpr int BI = (BN * BK / 8) / NT;
  __shared__ u16 As[2][BM * BK];
  __shared__ u16 Bs[2][BN * BK];
  const int tid = threadIdx.x;
  const int wave = tid >> 6, lane = tid & 63;
  const int r = lane & 15, g = lane >> 4;
  const int row0 = blockIdx.y * BM, col0 = blockIdx.x * BN;
  const int wr = (wave / WC) * WM, wc = (wave % WC) * WN;
  const int KS = K * SPLITK;
  const int kb0 = blockIdx.z * K;

  auto stage = [&](int kt, int p) {
#pragma unroll
    for (int i = 0; i < AI; ++i) {
      int bi = i * NT + wave * 64;
      int c = bi + lane;
      int row = c >> 3, ch = (c & 7) ^ (row & 7);
      gld_lds16(A + (size_t)(row0 + row) * KS + kb0 + kt + ch * 8, &As[p][(size_t)bi * 8]);
    }
#pragma unroll
    for (int i = 0; i < BI; ++i) {
      int bi = i * NT + wave * 64;
      int c = bi + lane;
      int row = c >> 3, ch = (c & 7) ^ (row & 7);
      gld_lds16(B + (size_t)(col0 + row) * KS + kb0 + kt + ch * 8, &Bs[p][(size_t)bi * 8]);
    }
  };

  f32x4 acc[MF][NF] = {};
  const int nt = K / BK;

  stage(0, 0);
  for (int t = 0; t < nt; ++t) {
    const int p = t & 1;
    bar_vm0();
    if (t + 1 < nt) stage((t + 1) * BK, p ^ 1);
    __builtin_amdgcn_s_setprio(1);
#pragma unroll
    for (int kk = 0; kk < 2; ++kk) {
      bf16x8 af[MF], bfv[NF];
#pragma unroll
      for (int m = 0; m < MF; ++m)
        af[m] = *(const bf16x8*)(&As[p][(wr + m * 16 + r) * BK + (((kk * 4 + g) ^ (r & 7))) * 8]);
#pragma unroll
      for (int n = 0; n < NF; ++n)
        bfv[n] = *(const bf16x8*)(&Bs[p][(wc + n * 16 + r) * BK + (((kk * 4 + g) ^ (r & 7))) * 8]);
#pragma unroll
      for (int m = 0; m < MF; ++m)
#pragma unroll
        for (int n = 0; n < NF; ++n)
          acc[m][n] = mfma_bf16(af[m], bfv[n], acc[m][n]);
    }
    __builtin_amdgcn_s_setprio(0);
  }

  const size_t moff = (size_t)blockIdx.z * gridDim.y * BM * N;
#pragma unroll
  for (int m = 0; m < MF; ++m) {
#pragma unroll
    for (int n = 0; n < NF; ++n) {
      int gcol = col0 + wc + n * 16 + r;
#pragma unroll
      for (int j = 0; j < 4; ++j) {
        int grow = row0 + wr + m * 16 + g * 4 + j;
        float val = acc[m][n][j];
        if constexpr (MODE == 0) {
          int he = gcol;
          val += bias0[he];
          int bb = grow >> 10, s = grow & 1023;
          size_t off = (((size_t)(bb * 8 + (he >> 9)) * 1024 + s) * 512) + (he & 511);
          ((u16*)out0)[off] = f2bf(val);
        } else if constexpr (MODE == 1) {
          val += bias0[grow];
          int bb = gcol >> 10, s = gcol & 1023;
          size_t off = (((size_t)bb * 8 + (grow >> 9)) * 512 + (grow & 511)) * 1024 + s;
          ((u16*)out0)[off] = f2bf(val);
        } else if constexpr (MODE == 2) {
          if (SPLITK == 1 || blockIdx.z == 0) val += bias0[gcol];
          ((float*)out0)[moff + (size_t)grow * N + gcol] = val;
        } else {
          float v2 = fmaxf(val + bias0[gcol], 0.0f);
          ((u16*)out0)[(size_t)grow * N + gcol] = f2bf(v2);
        }
      }
    }
  }
}

// ---------------- flash attention (v8 structure; K = raw xb shared by all heads) ----------
__global__ __launch_bounds__(512, 2) void flash_kernel(const u16* __restrict__ qg,
                                                       const u16* __restrict__ kg,
                                                       const u16* __restrict__ vtg,
                                                       u16* __restrict__ concat) {
  constexpr float SCALE = 0.04419417382415922f;  // 1/sqrt(512)
  __shared__ u16 Ks[2][32 * 512];
  __shared__ u16 Vs[2][32 * 512];
  __shared__ u32 PsU[8][256];

  const int tid = threadIdx.x;
  const int wave = tid >> 6, lane = tid & 63;
  const int r = lane & 15, g = lane >> 4;
  const int bx = blockIdx.x;
  const int xcd = bx & 7, slot = bx >> 3;
  const int bh = xcd * 4 + (slot >> 3);
  const int qt = slot & 7;
  const int bb = bh >> 3, hh = bh & 7;
  const size_t hbase = (size_t)bh * 1024 * 512;
  const u16* qp = qg + hbase;
  const u16* kp = kg + (size_t)bb * 1024 * 512;  // K = xb[b] (head-independent)
  const u16* vp = vtg + hbase;                   // v'^T [512][1024] per head
  const int q0 = qt * 128;

  bf16x8 q[16];
#pragma unroll
  for (int kk = 0; kk < 16; ++kk)
    q[kk] = *(const bf16x8*)(qp + (size_t)(q0 + wave * 16 + r) * 512 + kk * 32 + g * 8);

  const int krow8 = lane >> 3, kch = (lane & 7) ^ (lane >> 3);
  const int vrow4 = lane >> 2, vch = (lane & 3) ^ ((lane >> 3) & 3);
  auto stageKV = [&](int t, int p) {
    int kv = t * 32;
#pragma unroll
    for (int j = 0; j < 4; ++j) {
      int id = wave * 4 + j;
      gld_lds16(kp + (size_t)(kv + j * 8 + krow8) * 512 + wave * 64 + kch * 8,
                &Ks[p][id * 512]);
    }
#pragma unroll
    for (int j = 0; j < 4; ++j) {
      int n = wave * 4 + j;
      gld_lds16(vp + (size_t)(n * 16 + vrow4) * 1024 + kv + vch * 8, &Vs[p][n * 512]);
    }
  };

  f32x4 o[32] = {};
  float mrun = -1e30f, lrun = 0.f;

  stageKV(0, 0);

  const int krh = (r >> 3) * 512;
  const int ke0 = (r & 7) * 64 + ((g ^ (r & 7)) * 8);
  const int ke1 = (r & 7) * 64 + (((4 + g) ^ (r & 7)) * 8);
  const int voff = (r * 4 + (g ^ ((r >> 1) & 3))) * 8;

  for (int t = 0; t < 32; ++t) {
    const int p = t & 1;
    bar_vm0();
    if (t < 31) stageKV(t + 1, p ^ 1);

    __builtin_amdgcn_s_setprio(1);
    f32x4 a0 = {}, a1 = {}, b0 = {}, b1 = {};
#pragma unroll
    for (int kc = 0; kc < 8; ++kc) {
      const u16* kb = &Ks[p][kc * 2048 + krh];
      bf16x8 kf00 = *(const bf16x8*)(kb + ke0);
      bf16x8 kf01 = *(const bf16x8*)(kb + 1024 + ke0);
      bf16x8 kf10 = *(const bf16x8*)(kb + ke1);
      bf16x8 kf11 = *(const bf16x8*)(kb + 1024 + ke1);
      a0 = mfma_bf16(kf00, q[2 * kc], a0);
      b0 = mfma_bf16(kf01, q[2 * kc], b0);
      a1 = mfma_bf16(kf10, q[2 * kc + 1], a1);
      b1 = mfma_bf16(kf11, q[2 * kc + 1], b1);
    }
    __builtin_amdgcn_s_setprio(0);
    f32x4 s0 = a0 + a1;
    f32x4 s1 = b0 + b1;

    float m8 = -1e30f;
#pragma unroll
    for (int j = 0; j < 4; ++j) {
      s0[j] *= SCALE;
      s1[j] *= SCALE;
      m8 = fmaxf(m8, fmaxf(s0[j], s1[j]));
    }
    m8 = fmaxf(m8, __shfl_xor(m8, 16));
    m8 = fmaxf(m8, __shfl_xor(m8, 32));
    if (__any(m8 - mrun > 6.0f)) {
      float mn = fmaxf(mrun, m8);
      float rs = __expf(mrun - mn);
      mrun = mn;
      lrun *= rs;
#pragma unroll
      for (int j = 0; j < 4; ++j) {
        float rsj = __shfl(rs, (lane & 48) | (g * 4 + j));
#pragma unroll
        for (int n = 0; n < 32; ++n) o[n][j] *= rsj;
      }
    }
    f32x4 p0, p1;
    float ls = 0.f;
#pragma unroll
    for (int j = 0; j < 4; ++j) {
      p0[j] = __expf(s0[j] - mrun);
      p1[j] = __expf(s1[j] - mrun);
      ls += p0[j] + p1[j];
    }
    ls += __shfl_xor(ls, 16);
    ls += __shfl_xor(ls, 32);
    lrun += ls;

    {
      u32* pw = &PsU[wave][0];
      int base = r * 4 + (g & 1) * 2 + (g >> 1) * 64;
      pw[base + 0] = cvt_pk_bf16(p0[0], p0[1]);
      pw[base + 1] = cvt_pk_bf16(p0[2], p0[3]);
      pw[base + 128 + 0] = cvt_pk_bf16(p1[0], p1[1]);
      pw[base + 128 + 1] = cvt_pk_bf16(p1[2], p1[3]);
    }
    wait_lg0();

    bf16x8 pa = *(const bf16x8*)&PsU[wave][lane * 4];
    __builtin_amdgcn_s_setprio(1);
#pragma unroll
    for (int n = 0; n < 32; ++n) {
      bf16x8 bv = *(const bf16x8*)&Vs[p][n * 512 + voff];
      o[n] = mfma_bf16(pa, bv, o[n]);
    }
    __builtin_amdgcn_s_setprio(0);
  }

  float invl = 1.0f / lrun;
#pragma unroll
  for (int j = 0; j < 4; ++j) {
    float inv = __shfl(invl, (lane & 48) | (g * 4 + j));
    int srow = q0 + wave * 16 + g * 4 + j;
    size_t rowoff = ((size_t)bb * 1024 + srow) * 4096;
#pragma unroll
    for (int n = 0; n < 32; ++n) {
      int ocol = hh * 512 + n * 16 + r;
      concat[rowoff + ocol] = f2bf(o[n][j] * inv);
    }
  }
}

// ------- residual add + layernorm; optionally sums 8 bf16 head-chunks (cc8) + bias -------
__global__ __launch_bounds__(128) void add_ln_kernel(const float* __restrict__ xin,
                                                     const u16* __restrict__ cc8,
                                                     const float* __restrict__ addin,
                                                     const float* __restrict__ addin2,
                                                     const float* __restrict__ bias,
                                                     const float* __restrict__ gamma,
                                                     const float* __restrict__ beta,
                                                     float* __restrict__ yout,
                                                     u16* __restrict__ ybout) {
  int row = blockIdx.x;
  int t = threadIdx.x;
  float4 xv = ((const float4*)(xin + (size_t)row * 512))[t];
  float v0 = xv.x, v1 = xv.y, v2 = xv.z, v3 = xv.w;
  if (cc8) {
    const u16* cr = cc8 + (size_t)row * 4096 + t * 4;
#pragma unroll
    for (int h = 0; h < 8; ++h) {
      ushort4 u = *(const ushort4*)(cr + h * 512);
      v0 += bf2f(u.x); v1 += bf2f(u.y); v2 += bf2f(u.z); v3 += bf2f(u.w);
    }
  }
  if (addin) {
    float4 av = ((const float4*)(addin + (size_t)row * 512))[t];
    v0 += av.x; v1 += av.y; v2 += av.z; v3 += av.w;
  }
  if (addin2) {
    float4 bv2 = ((const float4*)(addin2 + (size_t)row * 512))[t];
    v0 += bv2.x; v1 += bv2.y; v2 += bv2.z; v3 += bv2.w;
  }
  if (bias) {
    float4 b4 = ((const float4*)bias)[t];
    v0 += b4.x; v1 += b4.y; v2 += b4.z; v3 += b4.w;
  }
  float s1 = v0 + v1 + v2 + v3;
  float s2 = v0 * v0 + v1 * v1 + v2 * v2 + v3 * v3;
#pragma unroll
  for (int d = 1; d < 64; d <<= 1) {
    s1 += __shfl_xor(s1, d);
    s2 += __shfl_xor(s2, d);
  }
  __shared__ float sh[4];
  int wv = t >> 6;
  if ((t & 63) == 0) { sh[wv * 2] = s1; sh[wv * 2 + 1] = s2; }
  __syncthreads();
  s1 = sh[0] + sh[2];
  s2 = sh[1] + sh[3];
  float mean = s1 * (1.0f / 512.0f);
  float var = s2 * (1.0f / 512.0f) - mean * mean;
  float rstd = rsqrtf(var + 1e-6f);
  float4 gv = ((const float4*)gamma)[t];
  float4 bv = ((const float4*)beta)[t];
  float o0 = (v0 - mean) * rstd * gv.x + bv.x;
  float o1 = (v1 - mean) * rstd * gv.y + bv.y;
  float o2 = (v2 - mean) * rstd * gv.z + bv.z;
  float o3 = (v3 - mean) * rstd * gv.w + bv.w;
  float4 ov; ov.x = o0; ov.y = o1; ov.z = o2; ov.w = o3;
  ((float4*)(yout + (size_t)row * 512))[t] = ov;
  if (ybout) {
    ushort4 ub;
    ub.x = f2bf(o0); ub.y = f2bf(o1); ub.z = f2bf(o2); ub.w = f2bf(o3);
    ((ushort4*)(ybout + (size_t)row * 512))[t] = ub;
  }
}

extern "C" void kernel_launch(void* const* d_in, const int* in_sizes, int n_in, void* d_out,
                              int out_size, void* d_ws, size_t ws_size, hipStream_t stream) {
  (void)in_sizes; (void)n_in; (void)out_size; (void)ws_size;
  const float* x   = (const float*)d_in[0];
  const float* Wq  = (const float*)d_in[1];
  const float* bq  = (const float*)d_in[2];
  const float* Wk  = (const float*)d_in[3];
  const float* bk  = (const float*)d_in[4];  // drops out of softmax (row-invariant terms)
  const float* Wv  = (const float*)d_in[5];
  const float* bv  = (const float*)d_in[6];
  const float* Wo  = (const float*)d_in[7];
  const float* bo  = (const float*)d_in[8];
  const float* g1  = (const float*)d_in[9];
  const float* be1 = (const float*)d_in[10];
  const float* W1  = (const float*)d_in[11];
  const float* b1  = (const float*)d_in[12];
  const float* W2  = (const float*)d_in[13];
  const float* b2  = (const float*)d_in[14];
  const float* g2  = (const float*)d_in[15];
  const float* be2 = (const float*)d_in[16];
  (void)bk;

  char* ws = (char*)d_ws;
  const size_t MB = 1024 * 1024;
  u16*   xb    = (u16*)(ws + 0);          // 4MB
  u16*   wqC   = (u16*)(ws + 4 * MB);     // 4MB
  u16*   wkC   = (u16*)(ws + 8 * MB);     // 4MB
  u16*   wvC   = (u16*)(ws + 12 * MB);    // 4MB
  u16*   woT   = (u16*)(ws + 16 * MB);    // 4MB
  u16*   w1T   = (u16*)(ws + 20 * MB);    // 2MB
  u16*   w2T   = (u16*)(ws + 22 * MB);    // 2MB
  float* biasP = (float*)(ws + 24 * MB);  // 16KB
  u16*   mhT   = (u16*)(ws + 26 * MB);    // 4MB
  u16*   nhT   = (u16*)(ws + 30 * MB);    // 4MB
  u16*   qb    = (u16*)(ws + 34 * MB);    // 32MB
  u16*   vTb   = (u16*)(ws + 66 * MB);    // 32MB
  u16*   cc    = (u16*)(ws + 98 * MB);    // 32MB
  float* y     = (float*)(ws + 4 * MB);   // 8MB (reuse wqC/wkC after precomputes)
  u16*   yb    = (u16*)(ws + 26 * MB);    // 4MB (reuse mhT after q2)
  u16*   ff1   = (u16*)(ws + 34 * MB);    // 16MB (reuse qb after flash)
  float* ff2a  = (float*)(ws + 50 * MB);  // 8MB
  float* ff2b  = (float*)(ws + 58 * MB);  // 8MB

  prep_kernel<<<12288, 256, 0, stream>>>(x, Wq, Wk, Wv, Wo, W1, W2, xb, wqC, wkC, wvC,
                                         woT, w1T, w2T);
  biasp_kernel<<<32, 256, 0, stream>>>(Wo, bv, biasP);
  // mhT[(h,dp),d] = sum_e Wk[h,dp,e]*Wq[h,d,e]  (= (Wq Wk^T)^T per head)
  gemm_bat<0><<<dim3(4, 32), 256, 0, stream>>>(wkC, wqC, mhT);
  // nhT[(h,e),d] = sum_e2 Wo[(h,e2),e]*Wv[h,d,e2]  (= (Wv Wo_h)^T per head)
  gemm_bat<1><<<dim3(4, 32), 256, 0, stream>>>(woT, wvC, nhT);
  // q2 = x @ Mh (+bq) -> [B,H,S,512] bf16
  gemm_tn<512, 256, 256, 128, 64, 0, 1><<<dim3(16, 16), 512, 0, stream>>>(xb, mhT, 4096, 512, qb, bq);
  // v'^T = (x @ Nh + biasP)^T -> [B,H,512,S] bf16
  gemm_tn<512, 256, 256, 128, 64, 1, 1><<<dim3(16, 16), 512, 0, stream>>>(nhT, xb, 4096, 512, vTb, biasP);
  // attention with K = xb (raw x, shared across heads)
  flash_kernel<<<256, 512, 0, stream>>>(qb, xb, vTb, cc);
  // LN1: x + sum_h heads'_h + bo
  add_ln_kernel<<<4096, 128, 0, stream>>>(x, cc, nullptr, nullptr, bo, g1, be1, y, yb);
  gemm_tn<256, 128, 128, 64, 64, 3, 1><<<dim3(16, 32), 256, 0, stream>>>(yb, w1T, 2048, 512, ff1, b1);
  gemm_tn<256, 64, 128, 32, 64, 2, 2><<<dim3(4, 64, 2), 256, 0, stream>>>(ff1, w2T, 512, 1024, ff2a, b2);
  add_ln_kernel<<<4096, 128, 0, stream>>>(y, nullptr, ff2a, ff2b, nullptr, g2, be2, (float*)d_out, nullptr);
}